// Round 5
// baseline (424.465 us; speedup 1.0000x reference)
//
#include <hip/hip_runtime.h>
#include <math.h>
#include <stdint.h>

#define TOK 65536
#define DIN 256
#define EDIM 512
#define KCB 2048
#define NTA 4096        // A m-tiles (65536/16)
#define NTB 128         // B n-tiles (2048/16)

// workspace layout (float offsets), 64-float aligned
#define OFF_MP   0u                     // M' fp32 [2048*256]
#define OFF_CP   524288u                // c' [2048]
#define OFF_Q    526336u                // Q [2048*256]
#define OFF_W2T  1050624u               // W2T [512*256]
#define OFF_U    1181696u               // u [512]
#define OFF_CQ   1182208u               // cQ [256]
#define OFF_PV   1182464u               // partial vals [16][65536]  (transposed!)
#define OFF_PI   2231040u               // partial idx  [16][65536]
#define OFF_AH   3279616u               // A packed bf16 [8][4096][512]
#define OFF_BH   11668224u              // B packed bf16 [8][128][512]
#define TOT_F    11930368u

typedef short short8 __attribute__((ext_vector_type(8)));
typedef float f32x4 __attribute__((ext_vector_type(4)));

__device__ __forceinline__ unsigned short bf16rne(float x) {
    uint32_t u = __float_as_uint(x);
    u += 0x7fffu + ((u >> 16) & 1u);
    return (unsigned short)(u >> 16);
}

// fused: zero loss scalar + usage bins, then prep1 work.
// blocks 0..511: e -> W2T[e][o], u[e];  512..767: o -> cQ[o]
__global__ void prep1_kernel(const float* __restrict__ W1, const float* __restrict__ W2,
                             const float* __restrict__ bn1_beta, const float* __restrict__ bn2_gamma,
                             const float* __restrict__ bn2_beta, const float* __restrict__ b2,
                             float* __restrict__ W2T, float* __restrict__ u, float* __restrict__ cQ,
                             float* __restrict__ out) {
    __shared__ float red[256];
    const int b = blockIdx.x, t = threadIdx.x;
    const int gid = b * 256 + t;
    if (gid == 0) out[0] = 0.0f;
    if (gid < KCB) out[1 + TOK * DIN + gid] = 0.0f;
    const float s = 1.0f / sqrtf(1.0f + 1e-5f);
    if (b < EDIM) {
        int e = b;
        W2T[e * DIN + t] = bn2_gamma[e] * s * W2[t * EDIM + e];
        float v = bn1_beta[t] * W1[e * DIN + t];
        red[t] = v; __syncthreads();
        for (int off = 128; off; off >>= 1) { if (t < off) red[t] += red[t + off]; __syncthreads(); }
        if (t == 0) u[e] = red[0];
    } else {
        int o = b - EDIM;
        float v = bn2_beta[t] * W2[o * EDIM + t] + bn2_beta[t + 256] * W2[o * EDIM + t + 256];
        red[t] = v; __syncthreads();
        for (int off = 128; off; off >>= 1) { if (t < off) red[t] += red[t + off]; __syncthreads(); }
        if (t == 0) cQ[o] = b2[o] + red[0];
    }
}

// per block: 4 codebook rows -> Mp fp32, Q fp32
__global__ __launch_bounds__(256) void prep2_kernel(const float* __restrict__ E, const float* __restrict__ W1,
                                                    const float* __restrict__ W2T, const float* __restrict__ bn1_gamma,
                                                    const float* __restrict__ cQ,
                                                    float* __restrict__ Mp, float* __restrict__ Q) {
    __shared__ float Elds[EDIM * 4];
    const int k0 = blockIdx.x * 4, t = threadIdx.x;
    const float4* src = (const float4*)(E + (size_t)k0 * EDIM);
    for (int i = t; i < 512; i += 256) {
        float4 v = src[i];
        int kk = i >> 7;
        int e = (i & 127) << 2;
        Elds[(e + 0) * 4 + kk] = v.x; Elds[(e + 1) * 4 + kk] = v.y;
        Elds[(e + 2) * 4 + kk] = v.z; Elds[(e + 3) * 4 + kk] = v.w;
    }
    __syncthreads();
    float m0 = 0, m1 = 0, m2 = 0, m3 = 0, q0 = 0, q1 = 0, q2 = 0, q3 = 0;
    for (int e = 0; e < EDIM; e++) {
        float4 ev = *(const float4*)&Elds[e * 4];
        float w1 = W1[e * DIN + t];
        float w2 = W2T[e * DIN + t];
        m0 += ev.x * w1; m1 += ev.y * w1; m2 += ev.z * w1; m3 += ev.w * w1;
        q0 += ev.x * w2; q1 += ev.y * w2; q2 += ev.z * w2; q3 += ev.w * w2;
    }
    const float s = 1.0f / sqrtf(1.0f + 1e-5f);
    const float gs = bn1_gamma[t] * s;
    const float cq = cQ[t];
    float mv[4] = {gs * m0, gs * m1, gs * m2, gs * m3};
    float qv[4] = {q0 + cq, q1 + cq, q2 + cq, q3 + cq};
#pragma unroll
    for (int i = 0; i < 4; i++) {
        Mp[(size_t)(k0 + i) * DIN + t] = mv[i];
        Q[(size_t)(k0 + i) * DIN + t] = qv[i];
    }
}

// c'[k] = sum_e E[k][e]*(b1[e]+u[e]) - 0.5*sum_e E[k][e]^2 ; one wave per row
__global__ __launch_bounds__(256) void prep3_kernel(const float* __restrict__ E, const float* __restrict__ b1,
                                                    const float* __restrict__ u, float* __restrict__ cp) {
    const int t = threadIdx.x, lane = t & 63;
    const int k = blockIdx.x * 4 + (t >> 6);
    const float4* er = (const float4*)(E + (size_t)k * EDIM);
    float sa = 0.0f, sb = 0.0f;
#pragma unroll
    for (int i = 0; i < 2; i++) {
        int j4 = lane * 2 + i;          // float4 index 0..127
        float4 ev = er[j4];
        int e = j4 * 4;
        sa += ev.x * (b1[e] + u[e]) + ev.y * (b1[e + 1] + u[e + 1])
            + ev.z * (b1[e + 2] + u[e + 2]) + ev.w * (b1[e + 3] + u[e + 3]);
        sb += ev.x * ev.x + ev.y * ev.y + ev.z * ev.z + ev.w * ev.w;
    }
    float v = sa - 0.5f * sb;
#pragma unroll
    for (int off = 32; off; off >>= 1) v += __shfl_down(v, off, 64);
    if (lane == 0) cp[k] = v;
}

// X[R x 256] fp32 -> bf16 in MFMA fragment-tile order:
// plane kc (0..7), tile tt (16 rows), 1KB block: lane L owns
// X[tt*16 + (L&15)][kc*32 + (L>>4)*8 + 0..7].
__global__ __launch_bounds__(256) void pack_kernel(const float* __restrict__ X,
                                                   unsigned short* __restrict__ Hp, int ntiles) {
    __shared__ __align__(16) unsigned short Hs[32 * 264];
    const int t = threadIdx.x;
    const int r0 = blockIdx.x * 32;
    const float4* src = (const float4*)(X + (size_t)r0 * DIN);
#pragma unroll
    for (int i = 0; i < 8; i++) {
        int id = i * 256 + t;
        int row = id >> 6, c4 = id & 63;
        float4 v = src[id];
        float f[4] = {v.x, v.y, v.z, v.w};
        ushort4 H;
        unsigned short* hp = (unsigned short*)&H;
#pragma unroll
        for (int j = 0; j < 4; j++) hp[j] = bf16rne(f[j]);
        *(ushort4*)&Hs[row * 264 + c4 * 4] = H;
    }
    __syncthreads();
    const int lane = t & 63, w = t >> 6;
#pragma unroll
    for (int q = 0; q < 4; q++) {
        int fb = q * 4 + w;              // 0..15
        int tl = fb >> 3, kc = fb & 7;
        int srow = tl * 16 + (lane & 15);
        int scol = kc * 32 + (lane >> 4) * 8;
        short8 vh = *(const short8*)&Hs[srow * 264 + scol];
        size_t off = ((size_t)kc * ntiles + (r0 >> 4) + tl) * 512 + lane * 8;
        *(short8*)&Hp[off] = vh;
    }
}

// MFMA scorer, direct global->VGPR fragment loads, XCD-swizzled grid so the
// 16 nb-blocks of one mb run on one XCD (A stays L2-resident), explicit
// 2-stage register double-buffer over kc. pval/pidx transposed [nb][m].
__global__ __launch_bounds__(256) void score_mfma_kernel(const unsigned short* __restrict__ Ah,
                                                         const unsigned short* __restrict__ Bh,
                                                         const float* __restrict__ cp,
                                                         float* __restrict__ pval, int* __restrict__ pidx) {
    __shared__ float ev[2 * 128];
    __shared__ int   ei[2 * 128];
    const int t = threadIdx.x, lane = t & 63, w = t >> 6;
    const int wm = w & 1, wn = w >> 1;
    const int b = blockIdx.x;
    const int nb = (b >> 3) & 15;                 // xcd = b&7 round-robin heuristic
    const int mb = (b & 7) + ((b >> 7) << 3);     // all 16 nb of an mb -> same xcd
    const int m0 = mb * 128;
    const int n0 = nb * 128;
    const int amt = (m0 >> 4) + wm * 4;
    const int bnt = nb * 8 + wn * 4;

    const short8* A8 = (const short8*)Ah; // frag = A8[(kc*NTA + tile)*64 + lane]
    const short8* B8 = (const short8*)Bh;

    f32x4 acc[4][4];
#pragma unroll
    for (int i = 0; i < 4; i++)
#pragma unroll
        for (int j = 0; j < 4; j++) acc[i][j] = (f32x4){0.f, 0.f, 0.f, 0.f};

    short8 af[2][4], bf[2][4];
#pragma unroll
    for (int mt = 0; mt < 4; mt++) af[0][mt] = A8[((size_t)0 * NTA + amt + mt) * 64 + lane];
#pragma unroll
    for (int nt = 0; nt < 4; nt++) bf[0][nt] = B8[((size_t)0 * NTB + bnt + nt) * 64 + lane];

#pragma unroll
    for (int kc = 0; kc < 8; kc++) {
        const int cur = kc & 1, nxt = cur ^ 1;
        if (kc < 7) {
#pragma unroll
            for (int mt = 0; mt < 4; mt++)
                af[nxt][mt] = A8[((size_t)(kc + 1) * NTA + amt + mt) * 64 + lane];
#pragma unroll
            for (int nt = 0; nt < 4; nt++)
                bf[nxt][nt] = B8[((size_t)(kc + 1) * NTB + bnt + nt) * 64 + lane];
        }
#pragma unroll
        for (int mt = 0; mt < 4; mt++)
#pragma unroll
            for (int nt = 0; nt < 4; nt++)
                acc[mt][nt] = __builtin_amdgcn_mfma_f32_16x16x32_bf16(af[cur][mt], bf[cur][nt], acc[mt][nt], 0, 0, 0);
    }

    // epilogue: add c', argmax over this block's 128 codes per row
    const int fr = lane & 15;
    const int colb = n0 + wn * 64 + fr;
    float cpv[4];
#pragma unroll
    for (int nt = 0; nt < 4; nt++) cpv[nt] = cp[colb + nt * 16];
#pragma unroll
    for (int mt = 0; mt < 4; mt++) {
#pragma unroll
        for (int r = 0; r < 4; r++) {
            float bv = acc[mt][0][r] + cpv[0];
            int bc = colb;
#pragma unroll
            for (int nt = 1; nt < 4; nt++) {
                float v = acc[mt][nt][r] + cpv[nt];
                if (v > bv) { bv = v; bc = colb + nt * 16; }
            }
#pragma unroll
            for (int xm = 1; xm < 16; xm <<= 1) {
                float ov = __shfl_xor(bv, xm, 64);
                int oc = __shfl_xor(bc, xm, 64);
                if (ov > bv || (ov == bv && oc < bc)) { bv = ov; bc = oc; }
            }
            if (fr == 0) {
                int row = wm * 64 + mt * 16 + ((lane >> 4) << 2) + r;
                ev[wn * 128 + row] = bv;
                ei[wn * 128 + row] = bc;
            }
        }
    }
    __syncthreads();
    if (t < 128) {
        float v0 = ev[t]; int c0 = ei[t];
        float v1 = ev[128 + t]; int c1 = ei[128 + t];
        if (v1 > v0) { v0 = v1; c0 = c1; }   // wn=1 cols strictly higher -> strict >
        pval[(size_t)nb * TOK + m0 + t] = v0;   // contiguous 128-float store
        pidx[(size_t)nb * TOK + m0 + t] = c0;
    }
}

// gather: per row, reduce 16 partials in-wave -> k, then Q[k] -> out,
// fused loss reduction + usage histogram. 8 rows per wave.
__global__ __launch_bounds__(256) void gather_out_kernel(const float* __restrict__ flat,
                                                         const float* __restrict__ Q,
                                                         const float* __restrict__ pval,
                                                         const int* __restrict__ pidx,
                                                         float* __restrict__ out) {
    const int t = threadIdx.x;
    const int lane = t & 63;
    const int gw = blockIdx.x * 4 + (t >> 6);   // 8192 waves, 8 rows each
    float lsum = 0.0f;
#pragma unroll
    for (int r = 0; r < 8; r++) {
        int row = gw * 8 + r;
        float v = pval[(size_t)(lane & 15) * TOK + row];
        int c = pidx[(size_t)(lane & 15) * TOK + row];
#pragma unroll
        for (int xm = 1; xm < 16; xm <<= 1) {
            float ov = __shfl_xor(v, xm, 64);
            int oc = __shfl_xor(c, xm, 64);
            if (ov > v || (ov == v && oc < c)) { v = ov; c = oc; }
        }
        int k = c;
        const float* qr = Q + (size_t)k * DIN;
        const float* xr = flat + (size_t)row * DIN;
        float* ob = out + 1 + (size_t)row * DIN;
#pragma unroll
        for (int cc = 0; cc < 4; cc++) {
            int j = lane + 64 * cc;
            float q = qr[j];
            float d = q - xr[j];
            lsum += d * d;
            ob[j] = q;
        }
        if (lane == 0) atomicAdd(out + 1 + TOK * DIN + k, 1.0f / (float)TOK);
    }
#pragma unroll
    for (int off = 32; off; off >>= 1) lsum += __shfl_down(lsum, off, 64);
    if (lane == 0) atomicAdd(out, lsum * (1.25f / (float)((size_t)TOK * DIN)));
}

extern "C" void kernel_launch(void* const* d_in, const int* in_sizes, int n_in,
                              void* d_out, int out_size, void* d_ws, size_t ws_size,
                              hipStream_t stream) {
    const float* inputs = (const float*)d_in[0];
    const float* bn1_gamma = (const float*)d_in[1];
    const float* bn1_beta  = (const float*)d_in[2];
    const float* W1 = (const float*)d_in[3];
    const float* b1 = (const float*)d_in[4];
    const float* E  = (const float*)d_in[5];
    const float* bn2_gamma = (const float*)d_in[6];
    const float* bn2_beta  = (const float*)d_in[7];
    const float* W2 = (const float*)d_in[8];
    const float* b2 = (const float*)d_in[9];

    float* ws = (float*)d_ws;
    float* Mp  = ws + OFF_MP;
    float* cp  = ws + OFF_CP;
    float* Q   = ws + OFF_Q;
    float* W2T = ws + OFF_W2T;
    float* u   = ws + OFF_U;
    float* cQ  = ws + OFF_CQ;
    float* pval = ws + OFF_PV;
    int* pidx   = (int*)(ws + OFF_PI);
    unsigned short* Ah = (unsigned short*)(ws + OFF_AH);
    unsigned short* Bh = (unsigned short*)(ws + OFF_BH);
    float* out = (float*)d_out;

    hipLaunchKernelGGL(prep1_kernel, dim3(768), dim3(256), 0, stream,
                       W1, W2, bn1_beta, bn2_gamma, bn2_beta, b2, W2T, u, cQ, out);
    hipLaunchKernelGGL(prep2_kernel, dim3(512), dim3(256), 0, stream,
                       E, W1, W2T, bn1_gamma, cQ, Mp, Q);
    hipLaunchKernelGGL(prep3_kernel, dim3(512), dim3(256), 0, stream, E, b1, u, cp);
    hipLaunchKernelGGL(pack_kernel, dim3(TOK / 32), dim3(256), 0, stream, inputs, Ah, NTA);
    hipLaunchKernelGGL(pack_kernel, dim3(KCB / 32), dim3(256), 0, stream, Mp, Bh, NTB);
    hipLaunchKernelGGL(score_mfma_kernel, dim3(8192), dim3(256), 0, stream,
                       Ah, Bh, cp, pval, pidx);
    hipLaunchKernelGGL(gather_out_kernel, dim3(2048), dim3(256), 0, stream,
                       inputs, Q, pval, pidx, out);
}